// Round 23
// baseline (215.543 us; speedup 1.0000x reference)
//
#include <hip/hip_runtime.h>

typedef __bf16 bf16x8 __attribute__((ext_vector_type(8)));
typedef float  f32x4  __attribute__((ext_vector_type(4)));

#define LOG2E 1.4426950408889634f

static __device__ __forceinline__ float fexp2(float x) { return __builtin_amdgcn_exp2f(x); }
static __device__ __forceinline__ float frcp(float x)  { return __builtin_amdgcn_rcpf(x); }
static __device__ __forceinline__ float fsigmoid(float x) { return frcp(1.0f + fexp2(-LOG2E * x)); }
static __device__ __forceinline__ float ftanh(float x)    { return 2.0f * frcp(1.0f + fexp2(-2.0f * LOG2E * x)) - 1.0f; }

// ---------------------------------------------------------------------------
// Prep (verified r10-r21): pack 4 [512x512] fp32 weights into bf16 16x16x32
// B-fragment order, GATE-CONTIGUOUS:
// Wp[(((cn*16+ks)*4+g)*64 + lt)*8 + e] = W_g[cn*16+(lt&15)][ks*32+(lt>>4)*8+e]
// ---------------------------------------------------------------------------
__global__ __launch_bounds__(256) void wpack(const float* __restrict__ Wf,
                                             const float* __restrict__ Wi,
                                             const float* __restrict__ Wg,
                                             const float* __restrict__ Wo,
                                             __bf16* __restrict__ Wp)
{
    int idx = blockIdx.x * 256 + threadIdx.x;      // [0, 131072)
    int kg  = idx & 63;                            // k-group of 8
    int j   = (idx >> 6) & 511;                    // weight row = output col
    int g   = idx >> 15;
    const float* src = (g == 0) ? Wf : (g == 1) ? Wi : (g == 2) ? Wg : Wo;
    const float4* s4 = (const float4*)(src + j * 512 + kg * 8);
    float4 v0 = s4[0], v1 = s4[1];
    bf16x8 o;
    o[0] = (__bf16)v0.x; o[1] = (__bf16)v0.y; o[2] = (__bf16)v0.z; o[3] = (__bf16)v0.w;
    o[4] = (__bf16)v1.x; o[5] = (__bf16)v1.y; o[6] = (__bf16)v1.z; o[7] = (__bf16)v1.w;
    int cn = j >> 4;                               // 16-col group
    int ks = kg >> 2;                              // K=32 step
    int lt = (j & 15) + (kg & 3) * 16;             // lane slot
    size_t dst = ((size_t)(((cn * 16 + ks) * 4 + g) * 64 + lt)) * 8;
    *(bf16x8*)(Wp + dst) = o;
}

// ---------------------------------------------------------------------------
// Persistent continuous-staging kernel (r22 structure, STWR hazard fixed).
// 256 blocks x 4 tiles (BM=64). 512 thr (8 waves), LDS = 2 x 64 KiB ping-pong.
// Wave: 64 rows x 16 cols x 4 gates, acc = 64 AGPR. Staging of tile t+1 is
// spread across tile t's K-steps; one barrier per tile. All loads share one
// in-order vmcnt stream with counted waits.
// RULE-18 FIX vs r22: STWR starts with sched_barrier(0) so its conversion
// VALU (reading STLD asm outputs) cannot hoist above the counted s_waitcnt
// that completes those loads (0x107 masks allow VALU crossing).
// ---------------------------------------------------------------------------
__global__ __launch_bounds__(512, 2) void lstm_main(
    const float* __restrict__ xin, const float* __restrict__ stm,
    const __bf16* __restrict__ Wp,
    const float* __restrict__ bfv, const float* __restrict__ biv,
    const float* __restrict__ bgv, const float* __restrict__ bov,
    float* __restrict__ out)
{
    __shared__ unsigned char zs[131072];           // two 64-KiB tile buffers
    const int tid  = threadIdx.x;
    const int lane = tid & 63;
    const int wv   = tid >> 6;                     // 0..7
    const int l15  = lane & 15;
    const int lq   = lane >> 4;                    // 0..3
    const int b    = blockIdx.x;                   // 0..255

    // A-read invariants (verified r5):
    const int kkoff = lq >> 1;                     // 0/1
    const int sl0   = l15 + (lq & 1) * 32;         // bit4 clear
    const int koffb = kkoff << 10;

    // staging invariants (verified r11): wave stages row rnd*8+wv, lane = kg
    const int st_kk  = lane >> 1;
    const int st_hi  = (lane & 1) << 5;
    const int st_xor = st_kk & 7;

#define LOADB(B0, B1, B2, B3, KS) { \
    const char* a_ = bp + (KS) * 4096; \
    asm volatile("global_load_dwordx4 %0, %4, off\n\t" \
                 "global_load_dwordx4 %1, %4, off offset:1024\n\t" \
                 "global_load_dwordx4 %2, %4, off offset:2048\n\t" \
                 "global_load_dwordx4 %3, %4, off offset:3072" \
                 : "=&v"(B0), "=&v"(B1), "=&v"(B2), "=&v"(B3) : "v"(a_)); }
#define STLD(X0, X1, S0, S1, RND, ROWB) { \
    const size_t off_ = ((size_t)(ROWB) + (size_t)((RND) * 8 + wv)) * 2048 + (size_t)lane * 32; \
    const char* xp_ = (const char*)xin + off_; \
    const char* sp_ = (const char*)stm + off_; \
    asm volatile("global_load_dwordx4 %0, %4, off\n\t" \
                 "global_load_dwordx4 %1, %4, off offset:16\n\t" \
                 "global_load_dwordx4 %2, %5, off\n\t" \
                 "global_load_dwordx4 %3, %5, off offset:16" \
                 : "=&v"(X0), "=&v"(X1), "=&v"(S0), "=&v"(S1) \
                 : "v"(xp_), "v"(sp_)); }
#define STWR(X0, X1, S0, S1, RND, BUF) { \
    __builtin_amdgcn_sched_barrier(0); /* rule-18 fence: pin cvt VALU after the counted wait */ \
    bf16x8 p_; \
    p_[0] = (__bf16)(X0[0] + S0[0]); p_[1] = (__bf16)(X0[1] + S0[1]); \
    p_[2] = (__bf16)(X0[2] + S0[2]); p_[3] = (__bf16)(X0[3] + S0[3]); \
    p_[4] = (__bf16)(X1[0] + S1[0]); p_[5] = (__bf16)(X1[1] + S1[1]); \
    p_[6] = (__bf16)(X1[2] + S1[2]); p_[7] = (__bf16)(X1[3] + S1[3]); \
    const int row_  = (RND) * 8 + wv; \
    const int byte_ = ((row_ >> 5) << 15) | (st_kk << 10) | \
                      ((((row_ & 31) + st_hi) ^ st_xor) << 4); \
    *(bf16x8*)((BUF) + byte_) = p_; }
#define WAITN(N) { asm volatile("s_waitcnt vmcnt(" #N ")"); __builtin_amdgcn_sched_barrier(0x107); }
#define DRAIN    { asm volatile("s_waitcnt vmcnt(0)"); __builtin_amdgcn_sched_barrier(0); }
#define DOMFMA(B0, B1, B2, B3, KS) { \
    const int kk7_ = ((2 * (KS)) & 7) | kkoff; \
    const int t0_  = ((sl0 ^ kk7_) << 4) + (KS) * 2048 + koffb; \
    bf16x8 a0_ = *(const bf16x8*)(bufc + t0_); \
    bf16x8 a1_ = *(const bf16x8*)(bufc + t0_ + 256); \
    bf16x8 a2_ = *(const bf16x8*)(bufc + 32768 + t0_); \
    bf16x8 a3_ = *(const bf16x8*)(bufc + 32768 + t0_ + 256); \
    __builtin_amdgcn_s_setprio(1); \
    acc[0][0] = __builtin_amdgcn_mfma_f32_16x16x32_bf16(a0_, B0, acc[0][0], 0, 0, 0); \
    acc[1][0] = __builtin_amdgcn_mfma_f32_16x16x32_bf16(a1_, B0, acc[1][0], 0, 0, 0); \
    acc[2][0] = __builtin_amdgcn_mfma_f32_16x16x32_bf16(a2_, B0, acc[2][0], 0, 0, 0); \
    acc[3][0] = __builtin_amdgcn_mfma_f32_16x16x32_bf16(a3_, B0, acc[3][0], 0, 0, 0); \
    acc[0][1] = __builtin_amdgcn_mfma_f32_16x16x32_bf16(a0_, B1, acc[0][1], 0, 0, 0); \
    acc[1][1] = __builtin_amdgcn_mfma_f32_16x16x32_bf16(a1_, B1, acc[1][1], 0, 0, 0); \
    acc[2][1] = __builtin_amdgcn_mfma_f32_16x16x32_bf16(a2_, B1, acc[2][1], 0, 0, 0); \
    acc[3][1] = __builtin_amdgcn_mfma_f32_16x16x32_bf16(a3_, B1, acc[3][1], 0, 0, 0); \
    acc[0][2] = __builtin_amdgcn_mfma_f32_16x16x32_bf16(a0_, B2, acc[0][2], 0, 0, 0); \
    acc[1][2] = __builtin_amdgcn_mfma_f32_16x16x32_bf16(a1_, B2, acc[1][2], 0, 0, 0); \
    acc[2][2] = __builtin_amdgcn_mfma_f32_16x16x32_bf16(a2_, B2, acc[2][2], 0, 0, 0); \
    acc[3][2] = __builtin_amdgcn_mfma_f32_16x16x32_bf16(a3_, B2, acc[3][2], 0, 0, 0); \
    acc[0][3] = __builtin_amdgcn_mfma_f32_16x16x32_bf16(a0_, B3, acc[0][3], 0, 0, 0); \
    acc[1][3] = __builtin_amdgcn_mfma_f32_16x16x32_bf16(a1_, B3, acc[1][3], 0, 0, 0); \
    acc[2][3] = __builtin_amdgcn_mfma_f32_16x16x32_bf16(a2_, B3, acc[2][3], 0, 0, 0); \
    acc[3][3] = __builtin_amdgcn_mfma_f32_16x16x32_bf16(a3_, B3, acc[3][3], 0, 0, 0); \
    __builtin_amdgcn_s_setprio(0); }
#define STEPE(K) { LOADB(Q0, Q1, Q2, Q3, (K) + 1) WAITN(4) DOMFMA(P0, P1, P2, P3, K) }
#define STEPO(K) { LOADB(P0, P1, P2, P3, (K) + 1) WAITN(4) DOMFMA(Q0, Q1, Q2, Q3, K) }

    f32x4 Xa0, Xa1, Sa0, Sa1;                      // staging set A (even rnds)
    f32x4 Xb0, Xb1, Sb0, Sb1;                      // staging set B (odd rnds)

    unsigned char* bufc = zs;                      // compute buffer
    unsigned char* bufn = zs + 65536;              // staging buffer

    // ---- prologue: stage tile b into bufc (2-deep pipelined) ----
    {
        const size_t prow = (size_t)b * 64;
        STLD(Xa0, Xa1, Sa0, Sa1, 0, prow)
        STLD(Xb0, Xb1, Sb0, Sb1, 1, prow)
        WAITN(4) STWR(Xa0, Xa1, Sa0, Sa1, 0, bufc) STLD(Xa0, Xa1, Sa0, Sa1, 2, prow)
        WAITN(4) STWR(Xb0, Xb1, Sb0, Sb1, 1, bufc) STLD(Xb0, Xb1, Sb0, Sb1, 3, prow)
        WAITN(4) STWR(Xa0, Xa1, Sa0, Sa1, 2, bufc) STLD(Xa0, Xa1, Sa0, Sa1, 4, prow)
        WAITN(4) STWR(Xb0, Xb1, Sb0, Sb1, 3, bufc) STLD(Xb0, Xb1, Sb0, Sb1, 5, prow)
        WAITN(4) STWR(Xa0, Xa1, Sa0, Sa1, 4, bufc) STLD(Xa0, Xa1, Sa0, Sa1, 6, prow)
        WAITN(4) STWR(Xb0, Xb1, Sb0, Sb1, 5, bufc) STLD(Xb0, Xb1, Sb0, Sb1, 7, prow)
        WAITN(4) STWR(Xa0, Xa1, Sa0, Sa1, 6, bufc)
        WAITN(0) STWR(Xb0, Xb1, Sb0, Sb1, 7, bufc)
        asm volatile("s_waitcnt lgkmcnt(0)" ::: "memory");
        __builtin_amdgcn_s_barrier();
        __builtin_amdgcn_sched_barrier(0);
    }

    #pragma unroll 1
    for (int t = 0; t < 4; ++t) {
        const int  tile = b + t * 256;
        const int  row0 = tile * 64;
        const bool stg  = (t < 3);
        const size_t nrow = (size_t)(tile + 256) * 64;

        #pragma unroll 1
        for (int ci = 0; ci < 4; ++ci) {
            const int cn   = ci * 8 + wv;          // 16-col group [0,32)
            const int colj = cn * 16 + l15;
            const char* bp = (const char*)Wp + (size_t)cn * 65536 + (size_t)lane * 16;

            float bias0 = bfv[colj], bias1 = biv[colj];
            float bias2 = bgv[colj], bias3 = bov[colj];
            f32x4 acc[4][4];                       // [m][gate] = 64 AGPR
            #pragma unroll
            for (int m = 0; m < 4; ++m) {
                #pragma unroll
                for (int r = 0; r < 4; ++r) {
                    acc[m][0][r] = bias0; acc[m][1][r] = bias1;
                    acc[m][2][r] = bias2; acc[m][3][r] = bias3;
                }
            }

            bf16x8 P0, P1, P2, P3;                 // B set even-ks
            bf16x8 Q0, Q1, Q2, Q3;                 // B set odd-ks

            DRAIN                                   // stores + bias loads out of the stream
            LOADB(P0, P1, P2, P3, 0)
            // s0: staging chunk A load rides under DOMFMA(0)
            if (stg) { STLD(Xa0, Xa1, Sa0, Sa1, 2 * ci, nrow)
                       LOADB(Q0, Q1, Q2, Q3, 1) WAITN(8) }
            else     { LOADB(Q0, Q1, Q2, Q3, 1) WAITN(4) }
            DOMFMA(P0, P1, P2, P3, 0)
            STEPO(1)
            STEPE(2)
            if (stg) { STWR(Xa0, Xa1, Sa0, Sa1, 2 * ci, bufn) }
            STEPO(3)
            STEPE(4) STEPO(5) STEPE(6) STEPO(7)
            // s8: staging chunk B
            if (stg) { STLD(Xb0, Xb1, Sb0, Sb1, 2 * ci + 1, nrow)
                       LOADB(Q0, Q1, Q2, Q3, 9) WAITN(8) }
            else     { LOADB(Q0, Q1, Q2, Q3, 9) WAITN(4) }
            DOMFMA(P0, P1, P2, P3, 8)
            STEPO(9)
            STEPE(10)
            if (stg) { STWR(Xb0, Xb1, Sb0, Sb1, 2 * ci + 1, bufn) }
            STEPO(11)
            STEPE(12) STEPO(13) STEPE(14)
            WAITN(0)
            DOMFMA(Q0, Q1, Q2, Q3, 15)

            // ---- epilogue (verified r5): col = l&15, row = lq*4 + r ----
            #pragma unroll
            for (int m = 0; m < 4; ++m) {
                #pragma unroll
                for (int r = 0; r < 4; ++r) {
                    float F = acc[m][0][r], I = acc[m][1][r];
                    float G = acc[m][2][r], O = acc[m][3][r];
                    float c = fsigmoid(F) + fsigmoid(I) * ftanh(G);
                    float h = ftanh(c) * fsigmoid(O);
                    int row = row0 + m * 16 + lq * 4 + r;
                    int o   = row * 512 + colj;
                    out[o] = c;
                    out[33554432 + o] = h;         // h plane at 65536*512
                }
            }
        }

        // ---- tile boundary: staging writes visible, swap buffers ----
        asm volatile("s_waitcnt lgkmcnt(0)" ::: "memory");
        __builtin_amdgcn_s_barrier();
        __builtin_amdgcn_sched_barrier(0);
        unsigned char* tmp = bufc; bufc = bufn; bufn = tmp;
    }
#undef LOADB
#undef STLD
#undef STWR
#undef WAITN
#undef DRAIN
#undef DOMFMA
#undef STEPE
#undef STEPO
}

extern "C" void kernel_launch(void* const* d_in, const int* in_sizes, int n_in,
                              void* d_out, int out_size, void* d_ws, size_t ws_size,
                              hipStream_t stream) {
    const float* xin = (const float*)d_in[0];
    const float* stm = (const float*)d_in[1];
    const float* Wf  = (const float*)d_in[2];
    const float* bf_ = (const float*)d_in[3];
    const float* Wi  = (const float*)d_in[4];
    const float* bi_ = (const float*)d_in[5];
    const float* Wg  = (const float*)d_in[6];
    const float* bg_ = (const float*)d_in[7];
    const float* Wo  = (const float*)d_in[8];
    const float* bo_ = (const float*)d_in[9];
    __bf16* Wp = (__bf16*)d_ws;                    // 2 MiB packed weights

    wpack<<<512, 256, 0, stream>>>(Wf, Wi, Wg, Wo, Wp);
    lstm_main<<<256, 512, 0, stream>>>(xin, stm, Wp, bf_, bi_, bg_, bo_, (float*)d_out);
}

// Round 24
// 174.479 us; speedup vs baseline: 1.2354x; 1.2354x over previous
//
#include <hip/hip_runtime.h>

typedef __bf16 bf16x8 __attribute__((ext_vector_type(8)));
typedef float  f32x4  __attribute__((ext_vector_type(4)));

#define LOG2E 1.4426950408889634f

static __device__ __forceinline__ float fexp2(float x) { return __builtin_amdgcn_exp2f(x); }
static __device__ __forceinline__ float frcp(float x)  { return __builtin_amdgcn_rcpf(x); }
static __device__ __forceinline__ float fsigmoid(float x) { return frcp(1.0f + fexp2(-LOG2E * x)); }
static __device__ __forceinline__ float ftanh(float x)    { return 2.0f * frcp(1.0f + fexp2(-2.0f * LOG2E * x)) - 1.0f; }

// ---------------------------------------------------------------------------
// Prep (verified r10-r23): pack 4 [512x512] fp32 weights into bf16 16x16x32
// B-fragment order, GATE-CONTIGUOUS:
// Wp[(((cn*16+ks)*4+g)*64 + lt)*8 + e] = W_g[cn*16+(lt&15)][ks*32+(lt>>4)*8+e]
// ---------------------------------------------------------------------------
__global__ __launch_bounds__(256) void wpack(const float* __restrict__ Wf,
                                             const float* __restrict__ Wi,
                                             const float* __restrict__ Wg,
                                             const float* __restrict__ Wo,
                                             __bf16* __restrict__ Wp)
{
    int idx = blockIdx.x * 256 + threadIdx.x;      // [0, 131072)
    int kg  = idx & 63;                            // k-group of 8
    int j   = (idx >> 6) & 511;                    // weight row = output col
    int g   = idx >> 15;
    const float* src = (g == 0) ? Wf : (g == 1) ? Wi : (g == 2) ? Wg : Wo;
    const float4* s4 = (const float4*)(src + j * 512 + kg * 8);
    float4 v0 = s4[0], v1 = s4[1];
    bf16x8 o;
    o[0] = (__bf16)v0.x; o[1] = (__bf16)v0.y; o[2] = (__bf16)v0.z; o[3] = (__bf16)v0.w;
    o[4] = (__bf16)v1.x; o[5] = (__bf16)v1.y; o[6] = (__bf16)v1.z; o[7] = (__bf16)v1.w;
    int cn = j >> 4;                               // 16-col group
    int ks = kg >> 2;                              // K=32 step
    int lt = (j & 15) + (kg & 3) * 16;             // lane slot
    size_t dst = ((size_t)(((cn * 16 + ks) * 4 + g) * 64 + lt)) * 8;
    *(bf16x8*)(Wp + dst) = o;
}

// ---------------------------------------------------------------------------
// Main fused kernel = r20 (176 us, best) with the ci=1..3 B pipeline deepened
// from 2 to 3 sets: steady-state s_waitcnt vmcnt(8) keeps TWO steps' loads in
// flight, giving each B batch ~1240 cyc of cover instead of ~620. ci=0 keeps
// r20's fused staging machinery verbatim. 512 thr, 128 KiB LDS, 2 waves/SIMD.
// ---------------------------------------------------------------------------
__global__ __launch_bounds__(512, 2) void lstm_main(
    const float* __restrict__ xin, const float* __restrict__ stm,
    const __bf16* __restrict__ Wp,
    const float* __restrict__ bfv, const float* __restrict__ biv,
    const float* __restrict__ bgv, const float* __restrict__ bov,
    float* __restrict__ out)
{
    __shared__ unsigned char zs[131072];           // 128 rows x 512 k, bf16, frag order
    const int tid  = threadIdx.x;
    const int lane = tid & 63;
    const int wv   = tid >> 6;                     // 0..7
    const int l15  = lane & 15;
    const int lq   = lane >> 4;                    // 0..3
    const int row0 = blockIdx.x * 128;

    // A-read invariants (verified r6/r18):
    const int kkoff = lq >> 1;                     // 0/1
    const int sl0   = l15 + (lq & 1) * 32;         // bit4 clear
    const int koffb = kkoff << 10;

    // staging invariants: thread covers (srow, kg = 4*slice + kgl), 8 k each
    const int srow   = tid >> 2;                   // 0..127
    const int kgl    = tid & 3;
    const int st_kh  = kgl >> 1;
    const int st_r31 = (srow & 31) + (kgl & 1) * 32;
    const int st_cb  = (srow >> 5) * 32768;
    const char* xq = (const char*)xin + ((size_t)(row0 + srow) * 512 + kgl * 8) * 4;
    const char* sq = (const char*)stm + ((size_t)(row0 + srow) * 512 + kgl * 8) * 4;

#define LOADB(B0, B1, B2, B3, KS) { \
    const char* a_ = bp + (KS) * 4096; \
    asm volatile("global_load_dwordx4 %0, %4, off\n\t" \
                 "global_load_dwordx4 %1, %4, off offset:1024\n\t" \
                 "global_load_dwordx4 %2, %4, off offset:2048\n\t" \
                 "global_load_dwordx4 %3, %4, off offset:3072" \
                 : "=&v"(B0), "=&v"(B1), "=&v"(B2), "=&v"(B3) : "v"(a_)); }
#define STLD(X0, X1, S0, S1, J) { \
    const char* xp_ = xq + (J) * 128; \
    const char* sp_ = sq + (J) * 128; \
    asm volatile("global_load_dwordx4 %0, %4, off\n\t" \
                 "global_load_dwordx4 %1, %4, off offset:16\n\t" \
                 "global_load_dwordx4 %2, %5, off\n\t" \
                 "global_load_dwordx4 %3, %5, off offset:16" \
                 : "=&v"(X0), "=&v"(X1), "=&v"(S0), "=&v"(S1) \
                 : "v"(xp_), "v"(sp_)); }
#define STWR(X0, X1, S0, S1, J) { \
    bf16x8 p_; \
    p_[0] = (__bf16)(X0[0] + S0[0]); p_[1] = (__bf16)(X0[1] + S0[1]); \
    p_[2] = (__bf16)(X0[2] + S0[2]); p_[3] = (__bf16)(X0[3] + S0[3]); \
    p_[4] = (__bf16)(X1[0] + S1[0]); p_[5] = (__bf16)(X1[1] + S1[1]); \
    p_[6] = (__bf16)(X1[2] + S1[2]); p_[7] = (__bf16)(X1[3] + S1[3]); \
    const int kk_ = 2 * (J) + st_kh; \
    *(bf16x8*)(zs + st_cb + kk_ * 1024 + ((st_r31 ^ (kk_ & 7)) << 4)) = p_; \
    asm volatile("s_waitcnt lgkmcnt(0)" ::: "memory"); \
    __builtin_amdgcn_s_barrier(); \
    __builtin_amdgcn_sched_barrier(0); }
#define WAITC(N) { asm volatile("s_waitcnt vmcnt(" #N ")"); __builtin_amdgcn_sched_barrier(0); }
#define WAITD(N) { asm volatile("s_waitcnt vmcnt(" #N ")"); __builtin_amdgcn_sched_barrier(0x107); }
#define WAITB8 { asm volatile("s_waitcnt vmcnt(8)"); __builtin_amdgcn_sched_barrier(0x107); }
#define WAITB4 { asm volatile("s_waitcnt vmcnt(4)"); __builtin_amdgcn_sched_barrier(0x107); }
#define WAITB0 { asm volatile("s_waitcnt vmcnt(0)"); __builtin_amdgcn_sched_barrier(0x107); }
#define DOMFMA(B0, B1, B2, B3, KS) { \
    const int kk7_ = ((2 * (KS)) & 7) | kkoff; \
    const int t0_  = ((sl0 ^ kk7_) << 4) + (KS) * 2048 + koffb; \
    { \
        bf16x8 a0_ = *(const bf16x8*)(zs + t0_); \
        bf16x8 a1_ = *(const bf16x8*)(zs + t0_ + 256); \
        bf16x8 a2_ = *(const bf16x8*)(zs + 32768 + t0_); \
        bf16x8 a3_ = *(const bf16x8*)(zs + 32768 + t0_ + 256); \
        __builtin_amdgcn_s_setprio(1); \
        acc[0][0] = __builtin_amdgcn_mfma_f32_16x16x32_bf16(a0_, B0, acc[0][0], 0, 0, 0); \
        acc[1][0] = __builtin_amdgcn_mfma_f32_16x16x32_bf16(a1_, B0, acc[1][0], 0, 0, 0); \
        acc[2][0] = __builtin_amdgcn_mfma_f32_16x16x32_bf16(a2_, B0, acc[2][0], 0, 0, 0); \
        acc[3][0] = __builtin_amdgcn_mfma_f32_16x16x32_bf16(a3_, B0, acc[3][0], 0, 0, 0); \
        acc[0][1] = __builtin_amdgcn_mfma_f32_16x16x32_bf16(a0_, B1, acc[0][1], 0, 0, 0); \
        acc[1][1] = __builtin_amdgcn_mfma_f32_16x16x32_bf16(a1_, B1, acc[1][1], 0, 0, 0); \
        acc[2][1] = __builtin_amdgcn_mfma_f32_16x16x32_bf16(a2_, B1, acc[2][1], 0, 0, 0); \
        acc[3][1] = __builtin_amdgcn_mfma_f32_16x16x32_bf16(a3_, B1, acc[3][1], 0, 0, 0); \
        acc[0][2] = __builtin_amdgcn_mfma_f32_16x16x32_bf16(a0_, B2, acc[0][2], 0, 0, 0); \
        acc[1][2] = __builtin_amdgcn_mfma_f32_16x16x32_bf16(a1_, B2, acc[1][2], 0, 0, 0); \
        acc[2][2] = __builtin_amdgcn_mfma_f32_16x16x32_bf16(a2_, B2, acc[2][2], 0, 0, 0); \
        acc[3][2] = __builtin_amdgcn_mfma_f32_16x16x32_bf16(a3_, B2, acc[3][2], 0, 0, 0); \
        acc[0][3] = __builtin_amdgcn_mfma_f32_16x16x32_bf16(a0_, B3, acc[0][3], 0, 0, 0); \
        acc[1][3] = __builtin_amdgcn_mfma_f32_16x16x32_bf16(a1_, B3, acc[1][3], 0, 0, 0); \
        acc[2][3] = __builtin_amdgcn_mfma_f32_16x16x32_bf16(a2_, B3, acc[2][3], 0, 0, 0); \
        acc[3][3] = __builtin_amdgcn_mfma_f32_16x16x32_bf16(a3_, B3, acc[3][3], 0, 0, 0); \
        __builtin_amdgcn_s_setprio(0); \
    } \
    { \
        bf16x8 a4_ = *(const bf16x8*)(zs + 65536 + t0_); \
        bf16x8 a5_ = *(const bf16x8*)(zs + 65536 + t0_ + 256); \
        bf16x8 a6_ = *(const bf16x8*)(zs + 98304 + t0_); \
        bf16x8 a7_ = *(const bf16x8*)(zs + 98304 + t0_ + 256); \
        __builtin_amdgcn_s_setprio(1); \
        acc[4][0] = __builtin_amdgcn_mfma_f32_16x16x32_bf16(a4_, B0, acc[4][0], 0, 0, 0); \
        acc[5][0] = __builtin_amdgcn_mfma_f32_16x16x32_bf16(a5_, B0, acc[5][0], 0, 0, 0); \
        acc[6][0] = __builtin_amdgcn_mfma_f32_16x16x32_bf16(a6_, B0, acc[6][0], 0, 0, 0); \
        acc[7][0] = __builtin_amdgcn_mfma_f32_16x16x32_bf16(a7_, B0, acc[7][0], 0, 0, 0); \
        acc[4][1] = __builtin_amdgcn_mfma_f32_16x16x32_bf16(a4_, B1, acc[4][1], 0, 0, 0); \
        acc[5][1] = __builtin_amdgcn_mfma_f32_16x16x32_bf16(a5_, B1, acc[5][1], 0, 0, 0); \
        acc[6][1] = __builtin_amdgcn_mfma_f32_16x16x32_bf16(a6_, B1, acc[6][1], 0, 0, 0); \
        acc[7][1] = __builtin_amdgcn_mfma_f32_16x16x32_bf16(a7_, B1, acc[7][1], 0, 0, 0); \
        acc[4][2] = __builtin_amdgcn_mfma_f32_16x16x32_bf16(a4_, B2, acc[4][2], 0, 0, 0); \
        acc[5][2] = __builtin_amdgcn_mfma_f32_16x16x32_bf16(a5_, B2, acc[5][2], 0, 0, 0); \
        acc[6][2] = __builtin_amdgcn_mfma_f32_16x16x32_bf16(a6_, B2, acc[6][2], 0, 0, 0); \
        acc[7][2] = __builtin_amdgcn_mfma_f32_16x16x32_bf16(a7_, B2, acc[7][2], 0, 0, 0); \
        acc[4][3] = __builtin_amdgcn_mfma_f32_16x16x32_bf16(a4_, B3, acc[4][3], 0, 0, 0); \
        acc[5][3] = __builtin_amdgcn_mfma_f32_16x16x32_bf16(a5_, B3, acc[5][3], 0, 0, 0); \
        acc[6][3] = __builtin_amdgcn_mfma_f32_16x16x32_bf16(a6_, B3, acc[6][3], 0, 0, 0); \
        acc[7][3] = __builtin_amdgcn_mfma_f32_16x16x32_bf16(a7_, B3, acc[7][3], 0, 0, 0); \
        __builtin_amdgcn_s_setprio(0); \
    } }
#define EPILOG \
    _Pragma("unroll") \
    for (int m = 0; m < 8; ++m) { \
        _Pragma("unroll") \
        for (int r = 0; r < 4; ++r) { \
            float F = acc[m][0][r], I = acc[m][1][r]; \
            float G = acc[m][2][r], O = acc[m][3][r]; \
            float c = fsigmoid(F) + fsigmoid(I) * ftanh(G); \
            float h = ftanh(c) * fsigmoid(O); \
            int row = row0 + m * 16 + lq * 4 + r; \
            int o   = row * 512 + colj; \
            out[o] = c; \
            out[33554432 + o] = h; \
        } }

    // ================= ci = 0: fused staging + K-loop (r20 verbatim) =======
    {
        const int cn   = wv;                       // 16-col group
        const int colj = cn * 16 + l15;
        const char* bp = (const char*)Wp + (size_t)cn * 65536 + (size_t)lane * 16;

        float bias0 = bfv[colj], bias1 = biv[colj];
        float bias2 = bgv[colj], bias3 = bov[colj];
        f32x4 acc[8][4];
        #pragma unroll
        for (int m = 0; m < 8; ++m) {
            #pragma unroll
            for (int r = 0; r < 4; ++r) {
                acc[m][0][r] = bias0; acc[m][1][r] = bias1;
                acc[m][2][r] = bias2; acc[m][3][r] = bias3;
            }
        }

        f32x4 Ax0, Ax1, As0, As1;                  // staging set A (even slices)
        f32x4 Bx0, Bx1, Bs0, Bs1;                  // staging set B (odd slices)
        bf16x8 P0, P1, P2, P3;                     // B set even-ks
        bf16x8 Q0, Q1, Q2, Q3;                     // B set odd-ks

        asm volatile("s_waitcnt vmcnt(0)");        // bias loads drained
        __builtin_amdgcn_sched_barrier(0);
        STLD(Ax0, Ax1, As0, As1, 0)
        STLD(Bx0, Bx1, Bs0, Bs1, 1)
        LOADB(P0, P1, P2, P3, 0)

#define CSTEP(J, JP1, JP2, N0,N1,N2,N3, C0,C1,C2,C3, SX0,SX1,SS0,SS1) \
        LOADB(N0, N1, N2, N3, JP1) \
        WAITC(12) \
        STWR(SX0, SX1, SS0, SS1, J) \
        STLD(SX0, SX1, SS0, SS1, JP2) \
        WAITD(12) \
        DOMFMA(C0, C1, C2, C3, J)

        // j = 0 (d-wait 8)
        LOADB(Q0, Q1, Q2, Q3, 1)
        WAITC(12)
        STWR(Ax0, Ax1, As0, As1, 0)
        STLD(Ax0, Ax1, As0, As1, 2)
        WAITD(8)
        DOMFMA(P0, P1, P2, P3, 0)
        // j = 1..13 general
        CSTEP( 1,  2,  3, P0,P1,P2,P3, Q0,Q1,Q2,Q3, Bx0,Bx1,Bs0,Bs1)
        CSTEP( 2,  3,  4, Q0,Q1,Q2,Q3, P0,P1,P2,P3, Ax0,Ax1,As0,As1)
        CSTEP( 3,  4,  5, P0,P1,P2,P3, Q0,Q1,Q2,Q3, Bx0,Bx1,Bs0,Bs1)
        CSTEP( 4,  5,  6, Q0,Q1,Q2,Q3, P0,P1,P2,P3, Ax0,Ax1,As0,As1)
        CSTEP( 5,  6,  7, P0,P1,P2,P3, Q0,Q1,Q2,Q3, Bx0,Bx1,Bs0,Bs1)
        CSTEP( 6,  7,  8, Q0,Q1,Q2,Q3, P0,P1,P2,P3, Ax0,Ax1,As0,As1)
        CSTEP( 7,  8,  9, P0,P1,P2,P3, Q0,Q1,Q2,Q3, Bx0,Bx1,Bs0,Bs1)
        CSTEP( 8,  9, 10, Q0,Q1,Q2,Q3, P0,P1,P2,P3, Ax0,Ax1,As0,As1)
        CSTEP( 9, 10, 11, P0,P1,P2,P3, Q0,Q1,Q2,Q3, Bx0,Bx1,Bs0,Bs1)
        CSTEP(10, 11, 12, Q0,Q1,Q2,Q3, P0,P1,P2,P3, Ax0,Ax1,As0,As1)
        CSTEP(11, 12, 13, P0,P1,P2,P3, Q0,Q1,Q2,Q3, Bx0,Bx1,Bs0,Bs1)
        CSTEP(12, 13, 14, Q0,Q1,Q2,Q3, P0,P1,P2,P3, Ax0,Ax1,As0,As1)
        CSTEP(13, 14, 15, P0,P1,P2,P3, Q0,Q1,Q2,Q3, Bx0,Bx1,Bs0,Bs1)
        // j = 14 (no STLD; d-wait 8)
        LOADB(Q0, Q1, Q2, Q3, 15)
        WAITC(12)
        STWR(Ax0, Ax1, As0, As1, 14)
        WAITD(8)
        DOMFMA(P0, P1, P2, P3, 14)
        // j = 15 (no LOADB/STLD; c-wait 4, d-wait 0)
        WAITC(4)
        STWR(Bx0, Bx1, Bs0, Bs1, 15)
        WAITD(0)
        DOMFMA(Q0, Q1, Q2, Q3, 15)
#undef CSTEP

        EPILOG
    }

    // ================= ci = 1..3: 3-deep B pipeline ========================
    for (int ci = 1; ci < 4; ++ci) {
        const int cn   = ci * 8 + wv;
        const int colj = cn * 16 + l15;
        const char* bp = (const char*)Wp + (size_t)cn * 65536 + (size_t)lane * 16;

        float bias0 = bfv[colj], bias1 = biv[colj];
        float bias2 = bgv[colj], bias3 = bov[colj];
        f32x4 acc[8][4];
        #pragma unroll
        for (int m = 0; m < 8; ++m) {
            #pragma unroll
            for (int r = 0; r < 4; ++r) {
                acc[m][0][r] = bias0; acc[m][1][r] = bias1;
                acc[m][2][r] = bias2; acc[m][3][r] = bias3;
            }
        }

        bf16x8 P0, P1, P2, P3;                     // set k%3 == 0
        bf16x8 Q0, Q1, Q2, Q3;                     // set k%3 == 1
        bf16x8 R0, R1, R2, R3;                     // set k%3 == 2

        asm volatile("s_waitcnt vmcnt(0)");        // stores + bias loads drained
        __builtin_amdgcn_sched_barrier(0);
        LOADB(P0, P1, P2, P3, 0)
        LOADB(Q0, Q1, Q2, Q3, 1)
#define T3(KC, C0,C1,C2,C3, N0,N1,N2,N3) \
        LOADB(N0, N1, N2, N3, (KC) + 2) WAITB8 DOMFMA(C0, C1, C2, C3, KC)
        T3( 0, P0,P1,P2,P3, R0,R1,R2,R3)
        T3( 1, Q0,Q1,Q2,Q3, P0,P1,P2,P3)
        T3( 2, R0,R1,R2,R3, Q0,Q1,Q2,Q3)
        T3( 3, P0,P1,P2,P3, R0,R1,R2,R3)
        T3( 4, Q0,Q1,Q2,Q3, P0,P1,P2,P3)
        T3( 5, R0,R1,R2,R3, Q0,Q1,Q2,Q3)
        T3( 6, P0,P1,P2,P3, R0,R1,R2,R3)
        T3( 7, Q0,Q1,Q2,Q3, P0,P1,P2,P3)
        T3( 8, R0,R1,R2,R3, Q0,Q1,Q2,Q3)
        T3( 9, P0,P1,P2,P3, R0,R1,R2,R3)
        T3(10, Q0,Q1,Q2,Q3, P0,P1,P2,P3)
        T3(11, R0,R1,R2,R3, Q0,Q1,Q2,Q3)
        T3(12, P0,P1,P2,P3, R0,R1,R2,R3)
        T3(13, Q0,Q1,Q2,Q3, P0,P1,P2,P3)
#undef T3
        WAITB4
        DOMFMA(R0, R1, R2, R3, 14)
        WAITB0
        DOMFMA(P0, P1, P2, P3, 15)

        EPILOG
    }
#undef LOADB
#undef STLD
#undef STWR
#undef WAITC
#undef WAITD
#undef WAITB8
#undef WAITB4
#undef WAITB0
#undef DOMFMA
#undef EPILOG
}

extern "C" void kernel_launch(void* const* d_in, const int* in_sizes, int n_in,
                              void* d_out, int out_size, void* d_ws, size_t ws_size,
                              hipStream_t stream) {
    const float* xin = (const float*)d_in[0];
    const float* stm = (const float*)d_in[1];
    const float* Wf  = (const float*)d_in[2];
    const float* bf_ = (const float*)d_in[3];
    const float* Wi  = (const float*)d_in[4];
    const float* bi_ = (const float*)d_in[5];
    const float* Wg  = (const float*)d_in[6];
    const float* bg_ = (const float*)d_in[7];
    const float* Wo  = (const float*)d_in[8];
    const float* bo_ = (const float*)d_in[9];
    __bf16* Wp = (__bf16*)d_ws;                    // 2 MiB packed weights

    wpack<<<512, 256, 0, stream>>>(Wf, Wi, Wg, Wo, Wp);
    lstm_main<<<512, 512, 0, stream>>>(xin, stm, Wp, bf_, bi_, bg_, bo_, (float*)d_out);
}